// Round 3
// baseline (1934.313 us; speedup 1.0000x reference)
//
#include <hip/hip_runtime.h>
#include <math.h>

// ---------------------------------------------------------------------------
// prep: Q0/Q1 state copies + scorer norms. grid 513 x 256. All fp32.
__launch_bounds__(256)
__global__ void prep_kernel(const float* __restrict__ q0, const float* __restrict__ q1,
                            const float* __restrict__ sc0, const float* __restrict__ sc1,
                            float* __restrict__ q0a, float* __restrict__ q1a,
                            float* __restrict__ sn){
  int b = blockIdx.x, tid = threadIdx.x;
  if (b < 256){ q0a[b*256 + tid] = q0[b*256 + tid]; }
  else if (b < 512){ int r = b - 256; q1a[r*256 + tid] = q1[r*256 + tid]; }
  else {
    __shared__ float s0[256], s1[256];
    float a = sc0[tid]; float c = sc1[tid];
    s0[tid] = a*a; s1[tid] = c*c; __syncthreads();
    for (int off = 128; off > 0; off >>= 1){
      if (tid < off){ s0[tid] += s0[tid+off]; s1[tid] += s1[tid+off]; }
      __syncthreads();
    }
    if (tid == 0){ sn[0] = sqrtf(s0[0]); sn[1] = sqrtf(s1[0]); }
  }
}

// ---------------------------------------------------------------------------
// ts[t][j] = tanh( dot(emb_t[j,:], scorer) / sn ) for j in 0..255
// block 256 = 4 waves, one j per wave; grid (64, nt)
__launch_bounds__(256)
__global__ void scores_kernel(const float* __restrict__ emb, long embStrideT,
                              const float* __restrict__ scorer,
                              const float* __restrict__ sn, int snIdx,
                              float* __restrict__ ts, int tsStrideT){
  int t = blockIdx.y;
  int wave = threadIdx.x >> 6, lane = threadIdx.x & 63;
  int j = blockIdx.x*4 + wave;
  const float* row = emb + (long)t*embStrideT + (long)j*256;
  float s = 0.f;
  for (int c = lane; c < 256; c += 64) s += row[c] * scorer[c];
  for (int off = 32; off > 0; off >>= 1) s += __shfl_down(s, off);
  if (lane == 0) ts[t*tsStrideT + j] = tanhf(s / sn[snIdx]);
}

// ---------------------------------------------------------------------------
// NN GEMM fp32: OUT[m][n] = sum_k A[m][k]*B[k][n].  A [Mx4096] lda 4096,
// B [4096x256] ldb 256. 32x32 tiles, 2x2 per thread. out fp32 ld 256.
// grid (M/32, 8, nt).
__launch_bounds__(256)
__global__ void gemm_nn_kernel(const float* __restrict__ A, long aTs,
                               const float* __restrict__ B, long bTs,
                               float* __restrict__ out, long oTs, int relu){
  int t = blockIdx.z;
  const float* At = A + (long)t*aTs;
  const float* Bt = B + (long)t*bTs;
  int m0 = blockIdx.x << 5, n0 = blockIdx.y << 5;
  int tid = threadIdx.x, tx = tid & 15, ty = tid >> 4;
  int rs = tid >> 3, c4 = tid & 7;          // 8 threads x float4 per 32-wide row
  __shared__ float sA[32][33];
  __shared__ float sB[32][33];
  float a00=0.f, a01=0.f, a10=0.f, a11=0.f;
  for (int k0 = 0; k0 < 4096; k0 += 32){
    float4 va = ((const float4*)(At + (long)(m0+rs)*4096 + k0))[c4];
    float4 vb = ((const float4*)(Bt + (long)(k0+rs)*256  + n0))[c4];
    int cs = c4 << 2;
    sA[rs][cs+0]=va.x; sA[rs][cs+1]=va.y; sA[rs][cs+2]=va.z; sA[rs][cs+3]=va.w;
    sB[rs][cs+0]=vb.x; sB[rs][cs+1]=vb.y; sB[rs][cs+2]=vb.z; sB[rs][cs+3]=vb.w;
    __syncthreads();
    #pragma unroll
    for (int k = 0; k < 32; k++){
      float x0=sA[ty][k], x1=sA[ty+16][k], y0=sB[k][tx], y1=sB[k][tx+16];
      a00 += x0*y0; a01 += x0*y1; a10 += x1*y0; a11 += x1*y1;
    }
    __syncthreads();
  }
  float* o = out + (long)t*oTs;
  if (relu){ a00=fmaxf(a00,0.f); a01=fmaxf(a01,0.f); a10=fmaxf(a10,0.f); a11=fmaxf(a11,0.f); }
  o[(long)(m0+ty   )*256 + n0+tx   ] = a00;
  o[(long)(m0+ty   )*256 + n0+tx+16] = a01;
  o[(long)(m0+ty+16)*256 + n0+tx   ] = a10;
  o[(long)(m0+ty+16)*256 + n0+tx+16] = a11;
}

// ---------------------------------------------------------------------------
// Gates: for g in {z(0), r(1), h(2)}:
//   accW[m][j] = sum_f W_g[m][f]*emb[j][f]   (NT; emb rows 0..255)
//   g<2:  G[g] = sigmoid(ts[j]*accW + sum_k U_g[m][k]*Q[k][j] + b_g[m][j])
//   g==2: G[2] = ts[j]*accW      (Wh@zt, raw)
// grid 192 = 3 groups x 64 tiles of 32x32; block 256. All fp32.
__launch_bounds__(256)
__global__ void gates_kernel(const float* __restrict__ emb,
                             const float* __restrict__ Wz, const float* __restrict__ Wr, const float* __restrict__ Wh,
                             const float* __restrict__ Uz, const float* __restrict__ Ur,
                             const float* __restrict__ bz, const float* __restrict__ br,
                             const float* __restrict__ Qcur, const float* __restrict__ ts,
                             float* __restrict__ G){
  int bx = blockIdx.x;
  int g = bx >> 6, tile = bx & 63;
  int m0 = (tile >> 3) << 5, j0 = (tile & 7) << 5;
  const float* W = (g==0) ? Wz : (g==1) ? Wr : Wh;
  int tid = threadIdx.x, tx = tid & 15, ty = tid >> 4;
  int rs = tid >> 3, cs = (tid & 7) << 2;
  __shared__ float sA[32][33];
  __shared__ float sB[32][33];
  float a00=0,a01=0,a10=0,a11=0;
  for (int k0 = 0; k0 < 256; k0 += 32){
    const float* pw = W   + (m0+rs)*256 + k0 + cs;
    const float* pe = emb + (long)(j0+rs)*256 + k0 + cs;
    sA[rs][cs+0]=pw[0]; sA[rs][cs+1]=pw[1]; sA[rs][cs+2]=pw[2]; sA[rs][cs+3]=pw[3];
    sB[cs+0][rs]=pe[0]; sB[cs+1][rs]=pe[1]; sB[cs+2][rs]=pe[2]; sB[cs+3][rs]=pe[3];
    __syncthreads();
    #pragma unroll
    for (int k = 0; k < 32; k++){
      float x0=sA[ty][k], x1=sA[ty+16][k], y0=sB[k][tx], y1=sB[k][tx+16];
      a00 += x0*y0; a01 += x0*y1; a10 += x1*y0; a11 += x1*y1;
    }
    __syncthreads();
  }
  float t0 = ts[j0+tx], t1 = ts[j0+tx+16];
  a00*=t0; a10*=t0; a01*=t1; a11*=t1;
  if (g == 2){
    G[2*65536 + (m0+ty   )*256 + j0+tx   ] = a00;
    G[2*65536 + (m0+ty   )*256 + j0+tx+16] = a01;
    G[2*65536 + (m0+ty+16)*256 + j0+tx   ] = a10;
    G[2*65536 + (m0+ty+16)*256 + j0+tx+16] = a11;
    return;
  }
  const float* U  = (g==0) ? Uz : Ur;
  const float* bb = (g==0) ? bz : br;
  float u00=0,u01=0,u10=0,u11=0;
  for (int k0 = 0; k0 < 256; k0 += 32){
    const float* pu = U    + (m0+rs)*256 + k0 + cs;
    const float* pq = Qcur + (k0+rs)*256 + j0 + cs;
    sA[rs][cs+0]=pu[0]; sA[rs][cs+1]=pu[1]; sA[rs][cs+2]=pu[2]; sA[rs][cs+3]=pu[3];
    sB[rs][cs+0]=pq[0]; sB[rs][cs+1]=pq[1]; sB[rs][cs+2]=pq[2]; sB[rs][cs+3]=pq[3];
    __syncthreads();
    #pragma unroll
    for (int k = 0; k < 32; k++){
      float x0=sA[ty][k], x1=sA[ty+16][k], y0=sB[k][tx], y1=sB[k][tx+16];
      u00 += x0*y0; u01 += x0*y1; u10 += x1*y0; u11 += x1*y1;
    }
    __syncthreads();
  }
  int m = m0+ty, j = j0+tx;
  float v;
  v = a00+u00+bb[m*256+j];          G[g*65536 + m*256+j]          = 1.f/(1.f+__expf(-v));
  v = a01+u01+bb[m*256+j+16];       G[g*65536 + m*256+j+16]       = 1.f/(1.f+__expf(-v));
  v = a10+u10+bb[(m+16)*256+j];     G[g*65536 + (m+16)*256+j]     = 1.f/(1.f+__expf(-v));
  v = a11+u11+bb[(m+16)*256+j+16];  G[g*65536 + (m+16)*256+j+16]  = 1.f/(1.f+__expf(-v));
}

// ---------------------------------------------------------------------------
// Update: Qnew = (1-z)*Q + z*tanh( Uh@(rst*Q) + G[2] + bh ). grid 64 tiles 32x32.
__launch_bounds__(256)
__global__ void update_kernel(const float* __restrict__ Uh, const float* __restrict__ bh,
                              const float* __restrict__ G, const float* __restrict__ Qcur,
                              float* __restrict__ Qnew){
  int tile = blockIdx.x;
  int m0 = (tile >> 3) << 5, j0 = (tile & 7) << 5;
  int tid = threadIdx.x, tx = tid & 15, ty = tid >> 4;
  int rs = tid >> 3, cs = (tid & 7) << 2;
  __shared__ float sA[32][33];
  __shared__ float sB[32][33];
  float a00=0,a01=0,a10=0,a11=0;
  for (int k0 = 0; k0 < 256; k0 += 32){
    const float* pu = Uh + (m0+rs)*256 + k0 + cs;
    const float* pr = G + 65536 + (k0+rs)*256 + j0 + cs;
    const float* pq = Qcur      + (k0+rs)*256 + j0 + cs;
    sA[rs][cs+0]=pu[0]; sA[rs][cs+1]=pu[1]; sA[rs][cs+2]=pu[2]; sA[rs][cs+3]=pu[3];
    sB[rs][cs+0]=pr[0]*pq[0]; sB[rs][cs+1]=pr[1]*pq[1]; sB[rs][cs+2]=pr[2]*pq[2]; sB[rs][cs+3]=pr[3]*pq[3];
    __syncthreads();
    #pragma unroll
    for (int k = 0; k < 32; k++){
      float x0=sA[ty][k], x1=sA[ty+16][k], y0=sB[k][tx], y1=sB[k][tx+16];
      a00 += x0*y0; a01 += x0*y1; a10 += x1*y0; a11 += x1*y1;
    }
    __syncthreads();
  }
  #pragma unroll
  for (int ii = 0; ii < 2; ii++){
    #pragma unroll
    for (int jj = 0; jj < 2; jj++){
      float acc = (ii==0) ? (jj==0?a00:a01) : (jj==0?a10:a11);
      int m = m0 + ty + ii*16, j = j0 + tx + jj*16;
      float h = tanhf(acc + G[2*65536 + m*256 + j] + bh[m*256+j]);
      float z = G[m*256 + j];
      float q = Qcur[m*256 + j];
      Qnew[m*256 + j] = (1.f - z)*q + z*h;
    }
  }
}

// ---------------------------------------------------------------------------
// Small fp32 GEMM C[m][n] = op(Amat[m,:] @ Bmat[:,n]); K=256. op: relu or none.
// Used for H1 = relu(Bm @ Q)  and  Z = H1 @ Q1.  grid (M/32)*8, tiles 32x32.
__launch_bounds__(256)
__global__ void small_gemm_kernel(const float* __restrict__ Am, const float* __restrict__ Bm,
                                  float* __restrict__ C, int relu){
  int bx = blockIdx.x;
  int m0 = (bx >> 3) << 5, j0 = (bx & 7) << 5;
  int tid = threadIdx.x, tx = tid & 15, ty = tid >> 4;
  int rs = tid >> 3, cs = (tid & 7) << 2;
  __shared__ float sA[32][33];
  __shared__ float sB[32][33];
  float a00=0,a01=0,a10=0,a11=0;
  for (int k0 = 0; k0 < 256; k0 += 32){
    const float* pa = Am + (long)(m0+rs)*256 + k0 + cs;
    const float* pb = Bm + (long)(k0+rs)*256 + j0 + cs;
    sA[rs][cs+0]=pa[0]; sA[rs][cs+1]=pa[1]; sA[rs][cs+2]=pa[2]; sA[rs][cs+3]=pa[3];
    sB[rs][cs+0]=pb[0]; sB[rs][cs+1]=pb[1]; sB[rs][cs+2]=pb[2]; sB[rs][cs+3]=pb[3];
    __syncthreads();
    #pragma unroll
    for (int k = 0; k < 32; k++){
      float x0=sA[ty][k], x1=sA[ty+16][k], y0=sB[k][tx], y1=sB[k][tx+16];
      a00 += x0*y0; a01 += x0*y1; a10 += x1*y0; a11 += x1*y1;
    }
    __syncthreads();
  }
  if (relu){ a00=fmaxf(a00,0.f); a01=fmaxf(a01,0.f); a10=fmaxf(a10,0.f); a11=fmaxf(a11,0.f); }
  C[(long)(m0+ty   )*256 + j0+tx   ] = a00;
  C[(long)(m0+ty   )*256 + j0+tx+16] = a01;
  C[(long)(m0+ty+16)*256 + j0+tx   ] = a10;
  C[(long)(m0+ty+16)*256 + j0+tx+16] = a11;
}

// ---------------------------------------------------------------------------
extern "C" void kernel_launch(void* const* d_in, const int* in_sizes, int n_in,
                              void* d_out, int out_size, void* d_ws, size_t ws_size,
                              hipStream_t stream){
  (void)in_sizes; (void)n_in; (void)out_size; (void)ws_size;
  const int N = 4096, F = 256;

  const float* A = (const float*)d_in[0];
  const float* X = (const float*)d_in[1];
  const float *SC[2], *WZ[2], *UZ[2], *BZ[2], *WR[2], *UR[2], *BR[2], *WH[2], *UH[2], *BH[2], *Q0I[2];
  for (int l = 0; l < 2; l++){
    int b = 3 + l*11;
    SC[l]  = (const float*)d_in[b+0];
    WZ[l]  = (const float*)d_in[b+1];  UZ[l] = (const float*)d_in[b+2];  BZ[l] = (const float*)d_in[b+3];
    WR[l]  = (const float*)d_in[b+4];  UR[l] = (const float*)d_in[b+5];  BR[l] = (const float*)d_in[b+6];
    WH[l]  = (const float*)d_in[b+7];  UH[l] = (const float*)d_in[b+8];  BH[l] = (const float*)d_in[b+9];
    Q0I[l] = (const float*)d_in[b+10];
  }

  char* w = (char*)d_ws;
  float* sn   = (float*)(w);                 // 2 floats (1 KiB slot)
  float* q0a  = (float*)(w + 1024);          // 256x256 fp32 x4 (ping-pong, both layers)
  float* q0b  = q0a + 65536;
  float* q1a  = q0b + 65536;
  float* q1b  = q1a + 65536;
  float* ts0  = q1b + 65536;                 // 8*256
  float* ts1  = ts0 + 2048;                  // 256
  float* G    = ts1 + 256;                   // 3*65536
  float* Bmat = G + 3*65536;                 // 7*65536
  float* C7   = Bmat + 7*65536;              // 4096*256 (reused as Z later)
  float* H1   = C7 + 1048576;                // 4096*256
  float* Z    = C7;                          // alias: C7 dead after t=7 h1
  // total ~12.1 MB

  // ---- parallel pre-phase ----
  prep_kernel<<<513, 256, 0, stream>>>(Q0I[0], Q0I[1], SC[0], SC[1], q0a, q1a, sn);
  scores_kernel<<<dim3(64, 8), 256, 0, stream>>>(X, (long)N*F, SC[0], sn, 0, ts0, 256);
  // B_t = A_t[:256] @ X_t  for t=0..6
  gemm_nn_kernel<<<dim3(8, 8, 7), 256, 0, stream>>>(A, (long)N*N, X, (long)N*F,
                                                    Bmat, 65536, 0);
  // C7 = A_7 @ X_7
  gemm_nn_kernel<<<dim3(128, 8, 1), 256, 0, stream>>>(A + (long)7*N*N, 0, X + (long)7*N*F, 0,
                                                      C7, 0, 0);

  // ---- sequential scan (both layers interleaved) ----
  float *q0c = q0a, *q0n = q0b, *q1c = q1a, *q1n = q1b;
  for (int t = 0; t < 8; t++){
    // layer 0 GRU step
    gates_kernel<<<192, 256, 0, stream>>>(X + (long)t*N*F, WZ[0], WR[0], WH[0], UZ[0], UR[0],
                                          BZ[0], BR[0], q0c, ts0 + t*256, G);
    update_kernel<<<64, 256, 0, stream>>>(UH[0], BH[0], G, q0c, q0n);
    // h1_t = relu(Bm @ Qn): rows 0..255 for t<7; full 4096 rows at t=7
    if (t < 7) small_gemm_kernel<<<64,   256, 0, stream>>>(Bmat + t*65536, q0n, H1, 1);
    else       small_gemm_kernel<<<1024, 256, 0, stream>>>(C7, q0n, H1, 1);
    // layer 1 GRU step
    scores_kernel<<<dim3(64, 1), 256, 0, stream>>>(H1, 0, SC[1], sn, 1, ts1, 0);
    gates_kernel<<<192, 256, 0, stream>>>(H1, WZ[1], WR[1], WH[1], UZ[1], UR[1],
                                          BZ[1], BR[1], q1c, ts1, G);
    update_kernel<<<64, 256, 0, stream>>>(UH[1], BH[1], G, q1c, q1n);
    float* tmp;
    tmp = q0c; q0c = q0n; q0n = tmp;
    tmp = q1c; q1c = q1n; q1n = tmp;
  }

  // ---- final output: out = relu(A_7 @ (H1_7 @ Q1)) ----
  small_gemm_kernel<<<1024, 256, 0, stream>>>(H1, q1c, Z, 0);
  gemm_nn_kernel<<<dim3(128, 8, 1), 256, 0, stream>>>(A + (long)7*N*N, 0, Z, 0,
                                                      (float*)d_out, 0, 1);
}